// Round 17
// baseline (120.513 us; speedup 1.0000x reference)
//
#include <hip/hip_runtime.h>
#include <hip/hip_fp16.h>
#include <math.h>

namespace {

constexpr int BB  = 4;    // batch
constexpr int SS  = 512;  // detector bins == image size
constexpr int AA  = 180;  // angles
constexpr int NJ  = 91;   // jobs: 89 pairs (a,180-a), a=1..89, + singles {0,90}
constexpr int RST = 520;  // row stride in 8B entries: [0,4) zeros, [4,516) data, [516,520) zeros

// ---------------------------------------------------------------------------
// Kernel A: zero `out` + ramp filter + 4-wide fp16 pack into padded rows.
// Job k: angles a1 = k+1, a2 = 179-k (k<89); singles k=89 -> a=0, k=90 -> a=90
// (a2 rows packed as zeros). Row entry[4+j] = (yA[j], yA[511-j], yB[j],
// yB[511-j]) as 4 x fp16 = 8 B. Conv math identical to R4-verified version.
// ---------------------------------------------------------------------------
__global__ __launch_bounds__(256) void ramp_zero_kernel(
    const float* __restrict__ x, uint2* __restrict__ xf, float* __restrict__ out) {
  const int t = threadIdx.x;
  const int k = blockIdx.x;   // job
  const int b = blockIdx.y;
  {  // zero out: 262144 float4 over 364 blocks
    const int bid = b * NJ + k;
    float4 z = make_float4(0.f, 0.f, 0.f, 0.f);
    for (int i = bid * 256 + t; i < (BB * SS * SS) / 4; i += 364 * 256)
      ((float4*)out)[i] = z;
  }
  const int a1 = (k < 89) ? (k + 1) : ((k == 89) ? 0 : 90);
  const int a2 = (k < 89) ? (179 - k) : a1;

  __shared__ __align__(16) float xs[2][2][256];  // [col][m-parity][m>>1]
  __shared__ __align__(16) float G[2][528];      // per-parity scaled taps
  __shared__ float yb[2][512];                   // filtered rows (both cols)

  const float s  = (float)(M_PI / 360.0);
  const float cc = (float)(-2.0 / (M_PI * M_PI)) * s;
  for (int i = t; i < 528; i += 256) {
    { int kk = i;     float d = (float)(2 * kk - 511); G[0][i] = (kk < 512) ? cc / (d * d) : 0.0f; }
    { int kk = i + 1; float d = (float)(2 * kk - 511); G[1][i] = (kk < 512) ? cc / (d * d) : 0.0f; }
  }

  const float* xb = x + (size_t)b * (SS * AA);
  {
    int m = t;
    xs[0][m & 1][m >> 1] = xb[(size_t)m * AA + a1];
    xs[1][m & 1][m >> 1] = xb[(size_t)m * AA + a2];
    m = t + 256;
    xs[0][m & 1][m >> 1] = xb[(size_t)m * AA + a1];
    xs[1][m & 1][m >> 1] = xb[(size_t)m * AA + a2];
  }
  __syncthreads();

  const int col = t >> 7;
  const int p   = (t >> 6) & 1;
  const int idx = t & 63;
  const float* Gp = G[p];
  const float* xv = xs[col][1 - p];

  float acc[4] = {0.f, 0.f, 0.f, 0.f};
  float W[8];  // W[s] = Gp[A0 + s], A0 = 4*idx + 252 - 4q; slot(r,d) = 3+r-d
  {
    const int A0 = 4 * idx + 252;
    float4 w0 = *(const float4*)(Gp + A0);
    float4 w1 = *(const float4*)(Gp + A0 + 4);
    W[0] = w0.x; W[1] = w0.y; W[2] = w0.z; W[3] = w0.w;
    W[4] = w1.x; W[5] = w1.y; W[6] = w1.z; W[7] = w1.w;
  }

#pragma unroll
  for (int q = 0; q < 64; ++q) {
    const float4 xq = *(const float4*)(xv + 4 * q);  // broadcast
    float4 nw;
    if (q != 63) nw = *(const float4*)(Gp + (4 * idx + 252 - 4 * (q + 1)));
#pragma unroll
    for (int r = 0; r < 4; ++r) {
      acc[r] = fmaf(W[3 + r], xq.x, acc[r]);
      acc[r] = fmaf(W[2 + r], xq.y, acc[r]);
      acc[r] = fmaf(W[1 + r], xq.z, acc[r]);
      acc[r] = fmaf(W[0 + r], xq.w, acc[r]);
    }
    if (q != 63) {
      W[7] = W[3]; W[6] = W[2]; W[5] = W[1]; W[4] = W[0];
      W[0] = nw.x; W[1] = nw.y; W[2] = nw.z; W[3] = nw.w;
    }
  }

  const float selfc = 0.5f * s;
  const float* xsp = xs[col][p];
#pragma unroll
  for (int r = 0; r < 4; ++r)
    yb[col][p + 8 * idx + 2 * r] = fmaf(selfc, xsp[4 * idx + r], acc[r]);
  __syncthreads();

  // write packed rows: 8 B per entry, coalesced
  uint2* orow = xf + (size_t)(b * NJ + k) * RST;
  const bool dual = (k < 89);
#pragma unroll
  for (int e = 0; e < 2; ++e) {
    int j = t + e * 256;
    __half2 lo = __floats2half2_rn(yb[0][j], yb[0][511 - j]);
    __half2 hi = dual ? __floats2half2_rn(yb[1][j], yb[1][511 - j])
                      : __floats2half2_rn(0.f, 0.f);
    uint2 u;
    __builtin_memcpy(&u.x, &lo, 4);
    __builtin_memcpy(&u.y, &hi, 4);
    orow[4 + j] = u;
  }
  if (t < 8) orow[(t < 4) ? t : (512 + t)] = make_uint2(0u, 0u);
}

// ---------------------------------------------------------------------------
// Kernel B: backprojection, four-fold symmetry (R16-verified math), but
// SINGLE-buffered wave-private LDS + 8 angle chunks:
//   R16 was 4 blocks/CU (33.5KB dbuf) with ~16us latency slack over the
//   ~17us DS floor. R17: buffer 16.6KB -> 8 blocks/CU = 32 waves/CU; grid
//   (4,16,32), ~11 jobs/chunk. Per-CU DS/VALU/DMA totals unchanged (2x waves
//   x 1/2 jobs); single-buffer serialization (wait vmcnt(0) -> compute ->
//   dma next) hidden by 8 waves/SIMD TLP. Explicit lgkmcnt(0) before each
//   DMA guards RAW on the shared buffer (free: compute consumed all DS data).
// __launch_bounds__(256,8) caps VGPR at 64 (est. ~55-60 used).
// ---------------------------------------------------------------------------
__global__ __launch_bounds__(256, 8) void backproject_kernel(
    const uint2* __restrict__ xf, float* __restrict__ out) {
  __shared__ __align__(16) uint2 bufs[4][RST];  // 16,640 B, wave-private
  __shared__ float2 trigS[12];

  const int t    = threadIdx.x;
  const int w    = t >> 6;
  const int lane = t & 63;
  const int tx   = blockIdx.x;     // 0..3  gx tile (64)
  const int ty   = blockIdx.y;     // 0..15 gy tile (16)
  const int b    = blockIdx.z >> 3;
  const int c    = blockIdx.z & 7; // job chunk (strided by 8)
  const int njobs = (91 - c + 7) >> 3;   // c<3: 12, else 11

  const float step = 2.0f / 511.0f;
  // early-exit quad tiles fully outside the circle (quadrant: x,y < 0)
  {
    float x1 = -1.0f + (float)(tx * 64 + 63) * step;
    float y1 = -1.0f + (float)(ty * 16 + 15) * step;
    if (x1 * x1 + y1 * y1 > 1.0f) return;  // out already zeroed
  }

  if (t < njobs) {
    int k = c + 8 * t;
    int a = (k < 89) ? (k + 1) : ((k == 89) ? 0 : 90);
    float sn, cn;
    sincosf((float)a * (float)(M_PI / 180.0), &sn, &cn);
    trigS[t] = make_float2(cn * 255.5f, sn * 255.5f);
  }
  __syncthreads();

  const uint2* rows = xf + (size_t)b * NJ * RST;
  auto dma = [&](int i) {
    const char* g0 = (const char*)(rows + (size_t)(c + 8 * i) * RST);
    char* l0 = (char*)&bufs[w][0];
#pragma unroll
    for (int sg = 0; sg < 4; ++sg)
      __builtin_amdgcn_global_load_lds(
          (const __attribute__((address_space(1))) void*)(g0 + sg * 1024 + lane * 16),
          (__attribute__((address_space(3))) void*)(l0 + sg * 1024), 16, 0, 0);
    if (lane < 4)
      __builtin_amdgcn_global_load_lds(
          (const __attribute__((address_space(1))) void*)(g0 + 4096 + lane * 16),
          (__attribute__((address_space(3))) void*)(l0 + 4096), 16, 0, 0);
  };

  const int gx = tx * 64 + lane;    // [0,256)
  // EXACT f32 replication of jnp.linspace for the MASK; p is continuity-safe.
  const float xg = __fadd_rn(-1.0f, __fmul_rn((float)gx, step));
  float yg[4];
#pragma unroll
  for (int kk = 0; kk < 4; ++kk)
    yg[kk] = __fadd_rn(-1.0f, __fmul_rn((float)(ty * 16 + w * 4 + kk), step));

  const float Kb = 255.5f + 4.0f;   // +4 = left pad
  const __half2 hz = __floats2half2_rn(0.f, 0.f);
  float f00[4] = {0, 0, 0, 0}, f11[4] = {0, 0, 0, 0};
  float f01[4] = {0, 0, 0, 0}, f10[4] = {0, 0, 0, 0};
  __half2 accA[4], accB[4], accC[4], accD[4];
#pragma unroll
  for (int kk = 0; kk < 4; ++kk) { accA[kk] = hz; accB[kk] = hz; accC[kk] = hz; accD[kk] = hz; }

  dma(0);

  for (int i = 0; i < njobs; ++i) {
    __builtin_amdgcn_s_waitcnt(0x0F70);  // vmcnt(0): buffer resident

    const float2 cs = trigS[i];
    const float m = fmaf(xg, cs.x, Kb);
    const uint2* R = bufs[w];
#pragma unroll
    for (int kk = 0; kk < 4; ++kk) {
      float P1 = fmaf(-yg[kk], cs.y, m);   // t1 = x c - y s (padded coords)
      float Pu = fmaf( yg[kk], cs.y, m);   // u  = x c + y s
      int I1 = (int)P1, Iu = (int)Pu;      // trunc==floor in-circle (P>=4)
#if __has_builtin(__builtin_amdgcn_fractf)
      float w1 = __builtin_amdgcn_fractf(P1);
      float wu = __builtin_amdgcn_fractf(Pu);
#else
      float w1 = P1 - floorf(P1);
      float wu = Pu - floorf(Pu);
#endif
      auto w1r = __builtin_amdgcn_cvt_pkrtz(w1, w1);
      auto wur = __builtin_amdgcn_cvt_pkrtz(wu, wu);
      __half2 w1h, wuh;
      __builtin_memcpy(&w1h, &w1r, 4);
      __builtin_memcpy(&wuh, &wur, 4);
      struct alignas(8) Q { __half2 lo, hi, lo2, hi2; } q1, qu;
      __builtin_memcpy(&q1, R + I1, 16);   // ds_read2_b64
      __builtin_memcpy(&qu, R + Iu, 16);
      accA[kk] = __hadd2(accA[kk], __hfma2(w1h, __hsub2(q1.lo2, q1.lo), q1.lo));
      accB[kk] = __hadd2(accB[kk], __hfma2(w1h, __hsub2(q1.hi2, q1.hi), q1.hi));
      accC[kk] = __hadd2(accC[kk], __hfma2(wuh, __hsub2(qu.lo2, qu.lo), qu.lo));
      accD[kk] = __hadd2(accD[kk], __hfma2(wuh, __hsub2(qu.hi2, qu.hi), qu.hi));
    }

    if ((i % 5) == 4 || i == njobs - 1) {  // flush fp16 accs (<=5 jobs) to f32
#pragma unroll
      for (int kk = 0; kk < 4; ++kk) {
        float2 fa = __half22float2(accA[kk]);  // ((x,y)@a,   (-x,-y)@a)
        float2 fb = __half22float2(accB[kk]);  // ((-x,y)@b,  (x,-y)@b)
        float2 fc = __half22float2(accC[kk]);  // ((x,-y)@a,  (-x,y)@a)
        float2 fd = __half22float2(accD[kk]);  // ((-x,-y)@b, (x,y)@b)
        f00[kk] += fa.x + fd.y;
        f11[kk] += fa.y + fd.x;
        f10[kk] += fb.x + fc.y;
        f01[kk] += fb.y + fc.x;
        accA[kk] = hz; accB[kk] = hz; accC[kk] = hz; accD[kk] = hz;
      }
    }

    if (i + 1 < njobs) {
      // all ds_reads of the buffer retired (data consumed by compute above);
      // make it explicit, then overwrite the single buffer with job i+1.
      __builtin_amdgcn_s_waitcnt(0xC07F);  // lgkmcnt(0), vmcnt(63), exp(7)
      dma(i + 1);
    }
  }

  // epilogue: per-pixel masks (exact f32 replication) + predicated atomics
  const int gxm  = 511 - gx;
  const float xgm = __fadd_rn(-1.0f, __fmul_rn((float)gxm, step));
  const float xx  = __fmul_rn(xg, xg);
  const float xxm = __fmul_rn(xgm, xgm);
#pragma unroll
  for (int kk = 0; kk < 4; ++kk) {
    int gy = ty * 16 + w * 4 + kk, gym = 511 - gy;
    float ygv = yg[kk];
    float ygm = __fadd_rn(-1.0f, __fmul_rn((float)gym, step));
    float yy  = __fmul_rn(ygv, ygv), yym = __fmul_rn(ygm, ygm);
    if (__fadd_rn(xx,  yy)  <= 1.0f) unsafeAtomicAdd(&out[((size_t)b * SS + gy ) * SS + gx ], f00[kk]);
    if (__fadd_rn(xxm, yym) <= 1.0f) unsafeAtomicAdd(&out[((size_t)b * SS + gym) * SS + gxm], f11[kk]);
    if (__fadd_rn(xx,  yym) <= 1.0f) unsafeAtomicAdd(&out[((size_t)b * SS + gym) * SS + gx ], f01[kk]);
    if (__fadd_rn(xxm, yy)  <= 1.0f) unsafeAtomicAdd(&out[((size_t)b * SS + gy ) * SS + gxm], f10[kk]);
  }
}

}  // namespace

extern "C" void kernel_launch(void* const* d_in, const int* in_sizes, int n_in,
                              void* d_out, int out_size, void* d_ws, size_t ws_size,
                              hipStream_t stream) {
  const float* x   = (const float*)d_in[0];
  float*       out = (float*)d_out;
  uint2*       xf  = (uint2*)d_ws;  // [B*91][520] x 8B = 1.51 MB

  ramp_zero_kernel<<<dim3(NJ, BB), 256, 0, stream>>>(x, xf, out);
  backproject_kernel<<<dim3(4, 16, 32), 256, 0, stream>>>(xf, out);
}

// Round 18
// 91.213 us; speedup vs baseline: 1.3212x; 1.3212x over previous
//
#include <hip/hip_runtime.h>
#include <hip/hip_fp16.h>
#include <math.h>

namespace {

constexpr int BB  = 4;    // batch
constexpr int SS  = 512;  // detector bins == image size
constexpr int AA  = 180;  // angles
constexpr int NJ  = 91;   // jobs: 89 pairs (a,180-a), a=1..89, + singles {0,90}

// ---------------------------------------------------------------------------
// Kernel A: zero `out` + ramp filter + OVERLAPPED 16B-entry pack.
// Job k: angles a1 = k+1, a2 = 179-k (k<89); singles k=89 -> a=0, k=90 -> 90.
// Row = 512 x 16B entries:
//   entry[j] = (A[j], A[511-j], B[j], B[511-j],      <- values at index j
//               A[j+1], A[510-j], B[j+1], B[510-j])  <- values at index j+1
// (out-of-range -> 0). One 16B-aligned ds_read_b128 then serves a full
// bilinear pair for 4 pixels x 2 angles (R16's two-address ds_read2_b64,
// ~2x cost, is what this removes). Conv math identical to R4-verified.
// ---------------------------------------------------------------------------
__global__ __launch_bounds__(256) void ramp_zero_kernel(
    const float* __restrict__ x, uint4* __restrict__ xf, float* __restrict__ out) {
  const int t = threadIdx.x;
  const int k = blockIdx.x;   // job
  const int b = blockIdx.y;
  {  // zero out: 262144 float4 over 364 blocks
    const int bid = b * NJ + k;
    float4 z = make_float4(0.f, 0.f, 0.f, 0.f);
    for (int i = bid * 256 + t; i < (BB * SS * SS) / 4; i += 364 * 256)
      ((float4*)out)[i] = z;
  }
  const int a1 = (k < 89) ? (k + 1) : ((k == 89) ? 0 : 90);
  const int a2 = (k < 89) ? (179 - k) : a1;

  __shared__ __align__(16) float xs[2][2][256];  // [col][m-parity][m>>1]
  __shared__ __align__(16) float G[2][528];      // per-parity scaled taps
  __shared__ float yb[2][512];                   // filtered rows (both cols)

  const float s  = (float)(M_PI / 360.0);
  const float cc = (float)(-2.0 / (M_PI * M_PI)) * s;
  for (int i = t; i < 528; i += 256) {
    { int kk = i;     float d = (float)(2 * kk - 511); G[0][i] = (kk < 512) ? cc / (d * d) : 0.0f; }
    { int kk = i + 1; float d = (float)(2 * kk - 511); G[1][i] = (kk < 512) ? cc / (d * d) : 0.0f; }
  }

  const float* xb = x + (size_t)b * (SS * AA);
  {
    int m = t;
    xs[0][m & 1][m >> 1] = xb[(size_t)m * AA + a1];
    xs[1][m & 1][m >> 1] = xb[(size_t)m * AA + a2];
    m = t + 256;
    xs[0][m & 1][m >> 1] = xb[(size_t)m * AA + a1];
    xs[1][m & 1][m >> 1] = xb[(size_t)m * AA + a2];
  }
  __syncthreads();

  const int col = t >> 7;
  const int p   = (t >> 6) & 1;
  const int idx = t & 63;
  const float* Gp = G[p];
  const float* xv = xs[col][1 - p];

  float acc[4] = {0.f, 0.f, 0.f, 0.f};
  float W[8];  // W[s] = Gp[A0 + s], A0 = 4*idx + 252 - 4q; slot(r,d) = 3+r-d
  {
    const int A0 = 4 * idx + 252;
    float4 w0 = *(const float4*)(Gp + A0);
    float4 w1 = *(const float4*)(Gp + A0 + 4);
    W[0] = w0.x; W[1] = w0.y; W[2] = w0.z; W[3] = w0.w;
    W[4] = w1.x; W[5] = w1.y; W[6] = w1.z; W[7] = w1.w;
  }

#pragma unroll
  for (int q = 0; q < 64; ++q) {
    const float4 xq = *(const float4*)(xv + 4 * q);  // broadcast
    float4 nw;
    if (q != 63) nw = *(const float4*)(Gp + (4 * idx + 252 - 4 * (q + 1)));
#pragma unroll
    for (int r = 0; r < 4; ++r) {
      acc[r] = fmaf(W[3 + r], xq.x, acc[r]);
      acc[r] = fmaf(W[2 + r], xq.y, acc[r]);
      acc[r] = fmaf(W[1 + r], xq.z, acc[r]);
      acc[r] = fmaf(W[0 + r], xq.w, acc[r]);
    }
    if (q != 63) {
      W[7] = W[3]; W[6] = W[2]; W[5] = W[1]; W[4] = W[0];
      W[0] = nw.x; W[1] = nw.y; W[2] = nw.z; W[3] = nw.w;
    }
  }

  const float selfc = 0.5f * s;
  const float* xsp = xs[col][p];
#pragma unroll
  for (int r = 0; r < 4; ++r)
    yb[col][p + 8 * idx + 2 * r] = fmaf(selfc, xsp[4 * idx + r], acc[r]);
  __syncthreads();

  // write overlapped 16B entries (coalesced dwordx4 stores)
  uint4* orow = xf + (size_t)(b * NJ + k) * 512;
  const bool dual = (k < 89);
#pragma unroll
  for (int e = 0; e < 2; ++e) {
    int j = t + e * 256;
    float Aj  = yb[0][j];
    float Ar  = yb[0][511 - j];
    float Aj1 = (j < 511) ? yb[0][j + 1]   : 0.f;
    float Ar1 = (j < 511) ? yb[0][510 - j] : 0.f;
    float Bj = 0.f, Br = 0.f, Bj1 = 0.f, Br1 = 0.f;
    if (dual) {
      Bj  = yb[1][j];
      Br  = yb[1][511 - j];
      Bj1 = (j < 511) ? yb[1][j + 1]   : 0.f;
      Br1 = (j < 511) ? yb[1][510 - j] : 0.f;
    }
    __half2 lo0 = __floats2half2_rn(Aj,  Ar);
    __half2 lo1 = __floats2half2_rn(Bj,  Br);
    __half2 hi0 = __floats2half2_rn(Aj1, Ar1);
    __half2 hi1 = __floats2half2_rn(Bj1, Br1);
    uint4 u;
    __builtin_memcpy(&u.x, &lo0, 4);
    __builtin_memcpy(&u.y, &lo1, 4);
    __builtin_memcpy(&u.z, &hi0, 4);
    __builtin_memcpy(&u.w, &hi1, 4);
    orow[j] = u;
  }
}

// ---------------------------------------------------------------------------
// Kernel B: backprojection, four-fold symmetry (R16-verified math), with
// single-address ds_read_b128 via overlapped rows + block-shared LDS dbuf.
// Grid (4,32,16) = 2048 blocks = 8/CU = 32 waves/CU; 4 atomic chunks (NOT 8:
// R17's 8-chunk atomics exploded WRITE 13->84MB). Per job: DMA prefetch of
// 8x1024B segments into buf^1 (2 segs/wave), compute on buf (2 kk x 2 reads),
// ONE __syncthreads (its vmcnt-drain is free: prefetch had all of compute to
// land). fp16 packed accumulators, f32 flush every 5 jobs (R16 numerics).
// ---------------------------------------------------------------------------
__global__ __launch_bounds__(256, 8) void backproject_kernel(
    const uint4* __restrict__ xf, float* __restrict__ out) {
  __shared__ __align__(16) uint4 bufs[2][512];  // 16 KB block-shared dbuf
  __shared__ float2 trigS[23];

  const int t    = threadIdx.x;
  const int w    = t >> 6;
  const int lane = t & 63;
  const int tx   = blockIdx.x;     // 0..3  gx tile (64)
  const int ty   = blockIdx.y;     // 0..31 gy tile (8)
  const int b    = blockIdx.z >> 2;
  const int c    = blockIdx.z & 3; // job chunk (strided by 4)
  const int njobs = (91 - c + 3) >> 2;   // c<3: 23, c=3: 22

  const float step = 2.0f / 511.0f;
  // early-exit quad tiles fully outside the circle (block-uniform, pre-barrier)
  {
    float x1 = -1.0f + (float)(tx * 64 + 63) * step;
    float y1 = -1.0f + (float)(ty * 8 + 7) * step;
    if (x1 * x1 + y1 * y1 > 1.0f) return;  // out already zeroed
  }

  if (t < njobs) {
    int k = c + 4 * t;
    int a = (k < 89) ? (k + 1) : ((k == 89) ? 0 : 90);
    float sn, cn;
    sincosf((float)a * (float)(M_PI / 180.0), &sn, &cn);
    trigS[t] = make_float2(cn * 255.5f, sn * 255.5f);
  }

  const uint4* rows = xf + (size_t)b * NJ * 512;
  // 8 segs of 1024B per row; wave w stages segs w and w+4.
  auto dma = [&](int i, int nb) {
    const char* g0 = (const char*)(rows + (size_t)(c + 4 * i) * 512);
    char* l0 = (char*)&bufs[nb][0];
    __builtin_amdgcn_global_load_lds(
        (const __attribute__((address_space(1))) void*)(g0 + w * 1024 + lane * 16),
        (__attribute__((address_space(3))) void*)(l0 + w * 1024), 16, 0, 0);
    __builtin_amdgcn_global_load_lds(
        (const __attribute__((address_space(1))) void*)(g0 + (w + 4) * 1024 + lane * 16),
        (__attribute__((address_space(3))) void*)(l0 + (w + 4) * 1024), 16, 0, 0);
  };

  const int gx = tx * 64 + lane;    // [0,256)
  // EXACT f32 replication of jnp.linspace for the MASK; p is continuity-safe.
  const float xg = __fadd_rn(-1.0f, __fmul_rn((float)gx, step));
  float yg[2];
#pragma unroll
  for (int kk = 0; kk < 2; ++kk)
    yg[kk] = __fadd_rn(-1.0f, __fmul_rn((float)(ty * 8 + w * 2 + kk), step));

  const float Kb = 255.5f;          // no pad: in-circle P = p in [0, 511]
  const __half2 hz = __floats2half2_rn(0.f, 0.f);
  float f00[2] = {0, 0}, f11[2] = {0, 0}, f01[2] = {0, 0}, f10[2] = {0, 0};
  __half2 accA[2], accB[2], accC[2], accD[2];
#pragma unroll
  for (int kk = 0; kk < 2; ++kk) { accA[kk] = hz; accB[kk] = hz; accC[kk] = hz; accD[kk] = hz; }

  dma(0, 0);
  __syncthreads();  // drains each wave's own DMAs; buf0 + trig resident

  int buf = 0;
  for (int i = 0; i < njobs; ++i) {
    const bool more = (i + 1 < njobs);
    if (more) dma(i + 1, buf ^ 1);  // prefetch; lands during compute below

    const float2 cs = trigS[i];
    const float m = fmaf(xg, cs.x, Kb);
    const uint4* R = bufs[buf];
#pragma unroll
    for (int kk = 0; kk < 2; ++kk) {
      float P1 = fmaf(-yg[kk], cs.y, m);   // t1 = x c - y s
      float Pu = fmaf( yg[kk], cs.y, m);   // u  = x c + y s
      int I1 = (int)P1, Iu = (int)Pu;      // trunc==floor in-circle (P>=0)
#if __has_builtin(__builtin_amdgcn_fractf)
      float w1 = __builtin_amdgcn_fractf(P1);
      float wu = __builtin_amdgcn_fractf(Pu);
#else
      float w1 = P1 - floorf(P1);
      float wu = Pu - floorf(Pu);
#endif
      auto w1r = __builtin_amdgcn_cvt_pkrtz(w1, w1);
      auto wur = __builtin_amdgcn_cvt_pkrtz(wu, wu);
      __half2 w1h, wuh;
      __builtin_memcpy(&w1h, &w1r, 4);
      __builtin_memcpy(&wuh, &wur, 4);
      struct alignas(16) Q { __half2 lo, hi, lo2, hi2; } q1, qu;
      __builtin_memcpy(&q1, R + I1, 16);   // ds_read_b128 (16B-aligned entry)
      __builtin_memcpy(&qu, R + Iu, 16);
      accA[kk] = __hadd2(accA[kk], __hfma2(w1h, __hsub2(q1.lo2, q1.lo), q1.lo));
      accB[kk] = __hadd2(accB[kk], __hfma2(w1h, __hsub2(q1.hi2, q1.hi), q1.hi));
      accC[kk] = __hadd2(accC[kk], __hfma2(wuh, __hsub2(qu.lo2, qu.lo), qu.lo));
      accD[kk] = __hadd2(accD[kk], __hfma2(wuh, __hsub2(qu.hi2, qu.hi), qu.hi));
    }

    if ((i % 5) == 4 || i == njobs - 1) {  // flush fp16 accs (<=5 jobs) to f32
#pragma unroll
      for (int kk = 0; kk < 2; ++kk) {
        float2 fa = __half22float2(accA[kk]);  // ((x,y)@a,   (-x,-y)@a)
        float2 fb = __half22float2(accB[kk]);  // ((-x,y)@b,  (x,-y)@b)
        float2 fc = __half22float2(accC[kk]);  // ((x,-y)@a,  (-x,y)@a)
        float2 fd = __half22float2(accD[kk]);  // ((-x,-y)@b, (x,y)@b)
        f00[kk] += fa.x + fd.y;
        f11[kk] += fa.y + fd.x;
        f10[kk] += fb.x + fc.y;
        f01[kk] += fb.y + fc.x;
        accA[kk] = hz; accB[kk] = hz; accC[kk] = hz; accD[kk] = hz;
      }
    }

    if (more) {
      __syncthreads();  // prefetch done (covered by compute); all reads of buf done
      buf ^= 1;
    }
  }

  // epilogue: per-pixel masks (exact f32 replication) + predicated atomics
  const int gxm  = 511 - gx;
  const float xgm = __fadd_rn(-1.0f, __fmul_rn((float)gxm, step));
  const float xx  = __fmul_rn(xg, xg);
  const float xxm = __fmul_rn(xgm, xgm);
#pragma unroll
  for (int kk = 0; kk < 2; ++kk) {
    int gy = ty * 8 + w * 2 + kk, gym = 511 - gy;
    float ygv = yg[kk];
    float ygm = __fadd_rn(-1.0f, __fmul_rn((float)gym, step));
    float yy  = __fmul_rn(ygv, ygv), yym = __fmul_rn(ygm, ygm);
    if (__fadd_rn(xx,  yy)  <= 1.0f) unsafeAtomicAdd(&out[((size_t)b * SS + gy ) * SS + gx ], f00[kk]);
    if (__fadd_rn(xxm, yym) <= 1.0f) unsafeAtomicAdd(&out[((size_t)b * SS + gym) * SS + gxm], f11[kk]);
    if (__fadd_rn(xx,  yym) <= 1.0f) unsafeAtomicAdd(&out[((size_t)b * SS + gym) * SS + gx ], f01[kk]);
    if (__fadd_rn(xxm, yy)  <= 1.0f) unsafeAtomicAdd(&out[((size_t)b * SS + gy ) * SS + gxm], f10[kk]);
  }
}

}  // namespace

extern "C" void kernel_launch(void* const* d_in, const int* in_sizes, int n_in,
                              void* d_out, int out_size, void* d_ws, size_t ws_size,
                              hipStream_t stream) {
  const float* x   = (const float*)d_in[0];
  float*       out = (float*)d_out;
  uint4*       xf  = (uint4*)d_ws;  // [B*91][512] x 16B = 2.98 MB

  ramp_zero_kernel<<<dim3(NJ, BB), 256, 0, stream>>>(x, xf, out);
  backproject_kernel<<<dim3(4, 32, 16), 256, 0, stream>>>(xf, out);
}